// Round 6
// baseline (351.869 us; speedup 1.0000x reference)
//
#include <hip/hip_runtime.h>
#include <math.h>

// Problem constants (from reference)
#define NWAY   10
#define DIMD   64
#define HWN    49           // H*W = 7*7
#define NSUP   800          // N_WAY*K_SHOT*PRJ
#define NQRY   16000        // N_WAY*Q_QUERY*PRJ
#define NTRI   2080         // 64*65/2
#define FEAT_PER (DIMD*HWN) // 3136 floats per sample
#define LDST   68           // fp32 dcov row stride (4-bank rotation, 16B-aligned)
#define KPAD   72           // bf16 row stride: 144 B/row -> 4-bank rotation
#define STP    12           // transposed support row stride (floats): 48 B

typedef __attribute__((ext_vector_type(8))) short bf16x8;
typedef __attribute__((ext_vector_type(4))) float f32x4;

// LDS: hl (staging) -> dcov (centered matrix, tail input) -> part (reduction)
// all overlaid; each transition is guarded by a __syncthreads().
// sizeof == 19456 B -> 8 blocks/CU fits in 160 KB LDS.
struct __align__(16) BDCShared {
    union {
        unsigned short hl[2*DIMD*KPAD];  // 18432 B: H[64][72], L[64][72]
        float dcov[DIMD*LDST];           // 17408 B: CENTERED dcov matrix
        float part[256*12];              // 12288 B: reduction partials (query tail)
    } u;
    float dg[DIMD];
    float rm[DIMD];
    float w4[4];            // per-wave partial for tm
    float red[16];          // final 11 sums
};

// Map linear triu index k -> (i,j), j>=i, row-major triu of 64x64 (init only).
__device__ __forceinline__ void k2ij(int k, int& io, int& jo) {
    int ii = (int)floorf((129.0f - sqrtf(16641.0f - 8.0f*(float)k)) * 0.5f);
    int off = ii*(129-ii)/2;
    if (off > k) { --ii; off = ii*(129-ii)/2; }
    else {
        int off2 = (ii+1)*(128-ii)/2;
        if (off2 <= k) { ii += 1; off = off2; }
    }
    io = ii;
    jo = ii + (k - off);
}

// HW packed bf16 convert (RNE): r.lo16 = bf16(a), r.hi16 = bf16(b)
__device__ __forceinline__ unsigned cvt_pk_bf16(float a, float b) {
    unsigned r;
    asm("v_cvt_pk_bf16_f32 %0, %1, %2" : "=v"(r) : "v"(a), "v"(b));
    return r;
}

// MFMA-based BDC. On return:
//   sm.u.dcov holds the full CENTERED dcov matrix (symmetric, stride LDST)
//   vJ[r] = centered value at (i = 16wv+4qd+r, j = 16J+c15) (register copy)
//   returns tm. Block = 256 threads = 4 waves.
__device__ __forceinline__ float bdc_compute(const float* __restrict__ feat,
                                             float et, int sample, BDCShared& sm,
                                             f32x4& v0, f32x4& v1, f32x4& v2,
                                             f32x4& v3) {
    const int tid = threadIdx.x;
    unsigned short* Hh = sm.u.hl;
    unsigned short* Lh = sm.u.hl + DIMD*KPAD;

    // ---- Stage: row-mapped. Thread owns (row d, quarter hq): 16 contiguous k.
    {
        const int d = tid & 63, hq = tid >> 6;       // hq is wave-uniform
        const float* rowp = feat + (size_t)sample * FEAT_PER + d*HWN + hq*16;
        float x[16];
        if (hq < 3) {
            #pragma unroll
            for (int i = 0; i < 16; ++i) x[i] = rowp[i];
        } else {
            x[0] = rowp[0];                          // k = 48
            #pragma unroll
            for (int i = 1; i < 16; ++i) x[i] = 0.0f;
        }
        unsigned hp[8], lp[8];
        #pragma unroll
        for (int i = 0; i < 8; ++i) {
            unsigned h = cvt_pk_bf16(x[2*i], x[2*i+1]);
            float h0 = __uint_as_float(h << 16);
            float h1 = __uint_as_float(h & 0xffff0000u);
            hp[i] = h;
            lp[i] = cvt_pk_bf16(x[2*i] - h0, x[2*i+1] - h1);
        }
        uint4* hd = (uint4*)&Hh[d*KPAD + hq*16];     // 144d+32hq B: 16B-aligned
        uint4* ld = (uint4*)&Lh[d*KPAD + hq*16];
        hd[0] = make_uint4(hp[0], hp[1], hp[2], hp[3]);
        hd[1] = make_uint4(hp[4], hp[5], hp[6], hp[7]);
        ld[0] = make_uint4(lp[0], lp[1], lp[2], lp[3]);
        ld[1] = make_uint4(lp[4], lp[5], lp[6], lp[7]);
    }
    __syncthreads();

    // ---- Gram via MFMA 16x16x32 bf16. Wave w owns G rows 16w..16w+15.
    const int wv = tid >> 6, lane = tid & 63;
    const int qd = lane >> 4, c15 = lane & 15;
    const int abase = (16*wv + c15)*KPAD + qd*8;
    bf16x8 AH0 = *(const bf16x8*)&Hh[abase];
    bf16x8 AH1 = *(const bf16x8*)&Hh[abase + 32];
    bf16x8 AL0 = *(const bf16x8*)&Lh[abase];
    bf16x8 AL1 = *(const bf16x8*)&Lh[abase + 32];

    f32x4 acc[4];                      // constant-indexed only (unrolled)
    #pragma unroll
    for (int J = 0; J < 4; ++J) {
        const int bbase = (16*J + c15)*KPAD + qd*8;
        bf16x8 BH0 = *(const bf16x8*)&Hh[bbase];
        bf16x8 BH1 = *(const bf16x8*)&Hh[bbase + 32];
        bf16x8 BL0 = *(const bf16x8*)&Lh[bbase];
        bf16x8 BL1 = *(const bf16x8*)&Lh[bbase + 32];
        f32x4 a = {0.f, 0.f, 0.f, 0.f};
        a = __builtin_amdgcn_mfma_f32_16x16x32_bf16(AH0, BH0, a, 0, 0, 0);
        a = __builtin_amdgcn_mfma_f32_16x16x32_bf16(AH1, BH1, a, 0, 0, 0);
        a = __builtin_amdgcn_mfma_f32_16x16x32_bf16(AL0, BH0, a, 0, 0, 0);
        a = __builtin_amdgcn_mfma_f32_16x16x32_bf16(AL1, BH1, a, 0, 0, 0);
        a = __builtin_amdgcn_mfma_f32_16x16x32_bf16(AH0, BL0, a, 0, 0, 0);
        a = __builtin_amdgcn_mfma_f32_16x16x32_bf16(AH1, BL1, a, 0, 0, 0);
        acc[J] = a;
    }

    // ---- dg from G diagonal (tile J == wv). C/D: col=lane&15, row=quad*4+reg.
    #pragma unroll
    for (int J = 0; J < 4; ++J) {
        if (J == wv) {
            #pragma unroll
            for (int r = 0; r < 4; ++r)
                if (c15 == 4*qd + r) sm.dg[16*wv + c15] = acc[J][r];
        }
    }
    __syncthreads();   // dg visible; all frag reads of u.hl done

    // ---- sqrt'd dcov in registers (v0..v3, uncentered) + in-register row sums
    f32x4 dgi = *(const f32x4*)&sm.dg[16*wv + 4*qd];
    float rs0 = 0.f, rs1 = 0.f, rs2 = 0.f, rs3 = 0.f;
#define DCOV_J(J, VJ)                                                          \
    {   float dgj = sm.dg[16*(J) + c15];                                       \
        _Pragma("unroll")                                                      \
        for (int r = 0; r < 4; ++r) {                                          \
            float t2 = fmaf(-2.0f, acc[J][r], dgi[r] + dgj);                   \
            t2 = fmaxf(t2, 0.0f);                                              \
            VJ[r] = __builtin_amdgcn_sqrtf(fmaf(et, t2, 1e-5f));               \
        }                                                                      \
        rs0 += VJ[0]; rs1 += VJ[1]; rs2 += VJ[2]; rs3 += VJ[3]; }
    DCOV_J(0, v0)
    DCOV_J(1, v1)
    DCOV_J(2, v2)
    DCOV_J(3, v3)
#undef DCOV_J

    // butterfly over the 16 c15-lanes: all lanes end with full row sums
    #pragma unroll
    for (int off = 1; off < 16; off <<= 1) {
        rs0 += __shfl_xor(rs0, off, 64);
        rs1 += __shfl_xor(rs1, off, 64);
        rs2 += __shfl_xor(rs2, off, 64);
        rs3 += __shfl_xor(rs3, off, 64);
    }
    if (c15 == 0) {
        f32x4 rmv = {rs0*(1.0f/64.0f), rs1*(1.0f/64.0f),
                     rs2*(1.0f/64.0f), rs3*(1.0f/64.0f)};
        *(f32x4*)&sm.rm[16*wv + 4*qd] = rmv;
    }
    float tt = (rs0 + rs1) + (rs2 + rs3);
    tt += __shfl_xor(tt, 16, 64);
    tt += __shfl_xor(tt, 32, 64);
    if (lane == 0) sm.w4[wv] = tt;
    __syncthreads();   // rm + w4 visible
    float tm = (sm.w4[0] + sm.w4[1] + sm.w4[2] + sm.w4[3]) * (1.0f/4096.0f);

    // ---- center in registers, write CENTERED matrix to LDS (transposed b128;
    // valid by symmetry). Tail then reads v directly -- no rm re-reads.
    const float rmi0 = rs0*(1.0f/64.0f), rmi1 = rs1*(1.0f/64.0f),
                rmi2 = rs2*(1.0f/64.0f), rmi3 = rs3*(1.0f/64.0f);
    float* dcov = sm.u.dcov;
    const int iB = 16*wv + 4*qd;
#define CENTER_J(J, VJ)                                                        \
    {   float rmj = sm.rm[16*(J) + c15] - tm;                                  \
        VJ[0] = VJ[0] - rmi0 - rmj;                                            \
        VJ[1] = VJ[1] - rmi1 - rmj;                                            \
        VJ[2] = VJ[2] - rmi2 - rmj;                                            \
        VJ[3] = VJ[3] - rmi3 - rmj;                                            \
        *(f32x4*)&dcov[(16*(J) + c15)*LDST + iB] = VJ; }
    CENTER_J(0, v0)
    CENTER_J(1, v1)
    CENTER_J(2, v2)
    CENTER_J(3, v3)
#undef CENTER_J
    __syncthreads();   // centered dcov visible
    return tm;
}

// init: build triu table (addr<<16 | i<<8 | j), zero s2 + loss slot
__global__ void kern_init(unsigned* __restrict__ table,
                          float* __restrict__ s2,
                          float* __restrict__ loss_slot) {
    int i = blockIdx.x * 256 + threadIdx.x;
    if (i < NTRI) {
        int ii, jj; k2ij(i, ii, jj);
        table[i] = ((unsigned)(ii*LDST + jj) << 16) | ((unsigned)ii << 8) | (unsigned)jj;
    }
    if (i < NWAY) s2[i] = 0.0f;
    if (i == 0) loss_slot[0] = 0.0f;
}

// Support: BDC -> centered triu vector scattered to global from registers.
// (256,8): VGPR 28 <= 64-cap, LDS 19456*8 <= 160K -> 8 blocks/CU resident.
__global__ __launch_bounds__(256, 8) void kern_support(const float* __restrict__ feat,
                                                       const float* __restrict__ temp,
                                                       float* __restrict__ tvout) {
    __shared__ BDCShared sm;
    float et = __expf(temp[0]);
    int s = blockIdx.x;                 // 0..799
    f32x4 v0, v1, v2, v3;
    bdc_compute(feat, et, s, sm, v0, v1, v2, v3);

    const int tid = threadIdx.x;
    const int wv = tid >> 6, lane = tid & 63;
    const int qd = lane >> 4, c15 = lane & 15;
    const int iB = 16*wv + 4*qd;
    float* dst = tvout + (size_t)s * NTRI;
#define SUP_J(J, VJ)                                                           \
    {   int j = 16*(J) + c15;                                                  \
        _Pragma("unroll")                                                      \
        for (int r = 0; r < 4; ++r) {                                          \
            int i = iB + r;                                                    \
            if (j >= i) dst[i*(129 - i)/2 + (j - i)] = VJ[r]; } }
    SUP_J(0, v0)
    SUP_J(1, v1)
    SUP_J(2, v2)
    SUP_J(3, v3)
#undef SUP_J
}

// Deterministic reduce: prototype means (transposed [k][12]) + s2.
// Grid = NWAY * 9 blocks; block (m, kc) handles k in [kc*256, kc*256+256).
__global__ __launch_bounds__(256) void kern_reduce(const float* __restrict__ tv,
                                                   const unsigned* __restrict__ table,
                                                   float* __restrict__ supT,
                                                   float* __restrict__ s2) {
    __shared__ float red[4];
    int m = blockIdx.x / 9, kc = blockIdx.x % 9;
    int k = kc*256 + threadIdx.x;
    float S = 0.0f;
    if (k < NTRI) {
        const float* p = tv + (size_t)(80*m) * NTRI + k;
        float a0 = 0.f, a1 = 0.f, a2 = 0.f, a3 = 0.f;
        for (int s4 = 0; s4 < 80; s4 += 4) {
            a0 += p[(size_t)(s4+0)*NTRI];
            a1 += p[(size_t)(s4+1)*NTRI];
            a2 += p[(size_t)(s4+2)*NTRI];
            a3 += p[(size_t)(s4+3)*NTRI];
        }
        S = ((a0+a1)+(a2+a3)) * (1.0f/80.0f);
        supT[k*STP + m] = S;
    }
    float ps = S * S;   // 0 for k >= NTRI
    int lane = threadIdx.x & 63, wv = threadIdx.x >> 6;
    #pragma unroll
    for (int off = 32; off > 0; off >>= 1) ps += __shfl_xor(ps, off, 64);
    if (lane == 0) red[wv] = ps;
    __syncthreads();
    if (threadIdx.x == 0) atomicAdd(&s2[m], red[0]+red[1]+red[2]+red[3]);
}

// Query: BDC (centered, in LDS) -> triu-table loop -> transpose reduce.
__global__ __launch_bounds__(256, 8) void kern_query(const float* __restrict__ feat,
                                                     const float* __restrict__ temp,
                                                     const unsigned* __restrict__ table,
                                                     const float* __restrict__ supT,
                                                     const float* __restrict__ s2,
                                                     float* __restrict__ out) {
    __shared__ BDCShared sm;
    float et = __expf(temp[0]);
    int qn = blockIdx.x;                // 0..15999
    f32x4 v0, v1, v2, v3;
    bdc_compute(feat, et, NSUP + qn, sm, v0, v1, v2, v3);

    const int tid = threadIdx.x;
    float qq = 0.0f;
    float cr[NWAY];                    // constant-indexed only (unrolled)
    #pragma unroll
    for (int m = 0; m < NWAY; ++m) cr[m] = 0.0f;

    const float* dcov = sm.u.dcov;
    for (int k = tid; k < NTRI; k += 256) {
        unsigned t = table[k];
        float v = dcov[t >> 16];       // already centered
        qq = fmaf(v, v, qq);
        const float4* sp = (const float4*)(supT + (size_t)k * STP);
        float4 sa = sp[0], sb = sp[1], sc = sp[2];   // cols 10,11 pad
        cr[0] = fmaf(v, sa.x, cr[0]);
        cr[1] = fmaf(v, sa.y, cr[1]);
        cr[2] = fmaf(v, sa.z, cr[2]);
        cr[3] = fmaf(v, sa.w, cr[3]);
        cr[4] = fmaf(v, sb.x, cr[4]);
        cr[5] = fmaf(v, sb.y, cr[5]);
        cr[6] = fmaf(v, sb.z, cr[6]);
        cr[7] = fmaf(v, sb.w, cr[7]);
        cr[8] = fmaf(v, sc.x, cr[8]);
        cr[9] = fmaf(v, sc.y, cr[9]);
    }
    __syncthreads();                   // all dcov reads done -> part overlay safe

    // LDS transpose reduce: 3x b128 write/thread, 176 threads gather, 4-step shfl
    float* part = sm.u.part;
    f32x4 p0 = {cr[0], cr[1], cr[2], cr[3]};
    f32x4 p1 = {cr[4], cr[5], cr[6], cr[7]};
    f32x4 p2 = {cr[8], cr[9], qq, 0.0f};
    *(f32x4*)&part[tid*12 + 0] = p0;
    *(f32x4*)&part[tid*12 + 4] = p1;
    *(f32x4*)&part[tid*12 + 8] = p2;
    __syncthreads();
    if (tid < 176) {
        int m = tid >> 4, g = tid & 15;
        float s = 0.0f;
        #pragma unroll
        for (int t = 0; t < 16; ++t) s += part[(g + 16*t)*12 + m];
        #pragma unroll
        for (int off = 1; off < 16; off <<= 1) s += __shfl_xor(s, off, 64);
        if (g == 0) sm.red[m] = s;
    }
    __syncthreads();
    if (tid < NWAY)
        out[(size_t)qn * NWAY + tid] = -(sm.red[10] + s2[tid] - 2.0f*sm.red[tid]);
}

// Softmax NLL partials: one atomicAdd per block.
__global__ __launch_bounds__(256) void kern_loss(const float* __restrict__ score,
                                                 const int* __restrict__ label,
                                                 float* __restrict__ loss_out) {
    __shared__ float red[4];
    int n = blockIdx.x * 256 + threadIdx.x;
    float lsum = 0.0f;
    if (n < NQRY) {
        const float* srow = score + (size_t)n * NWAY;
        float s[NWAY];
        float mx = -1e30f;
        #pragma unroll
        for (int m = 0; m < NWAY; ++m) { s[m] = srow[m]; mx = fmaxf(mx, s[m]); }
        float se = 0.0f;
        #pragma unroll
        for (int m = 0; m < NWAY; ++m) se += __expf(s[m] - mx);
        float lse = mx + __logf(se);
        lsum = lse - s[label[n]];
    }
    int lane = threadIdx.x & 63, wv = threadIdx.x >> 6;
    #pragma unroll
    for (int off = 32; off > 0; off >>= 1) lsum += __shfl_xor(lsum, off, 64);
    if (lane == 0) red[wv] = lsum;
    __syncthreads();
    if (threadIdx.x == 0)
        atomicAdd(loss_out, (red[0] + red[1] + red[2] + red[3]) * (1.0f / (float)NQRY));
}

extern "C" void kernel_launch(void* const* d_in, const int* in_sizes, int n_in,
                              void* d_out, int out_size, void* d_ws, size_t ws_size,
                              hipStream_t stream) {
    (void)in_sizes; (void)n_in; (void)out_size; (void)ws_size;
    const float* feat = (const float*)d_in[0];
    const float* temp = (const float*)d_in[1];
    const int*   label = (const int*)d_in[2];
    float* out = (float*)d_out;

    // workspace layout (~6.8 MB):
    float*    tv    = (float*)d_ws;                  // 800*2080 f = 6.656 MB
    float*    supT  = tv + (size_t)NSUP * NTRI;      // 2080*12 f (transposed+pad)
    float*    s2    = supT + NTRI*STP;               // 10 f (+pad)
    unsigned* table = (unsigned*)(s2 + 16);          // 2080 u32
    float* loss_slot = out + (size_t)NQRY * NWAY;

    kern_init<<<(NTRI + 255)/256, 256, 0, stream>>>(table, s2, loss_slot);
    kern_support<<<NSUP, 256, 0, stream>>>(feat, temp, tv);
    kern_reduce<<<NWAY*9, 256, 0, stream>>>(tv, table, supT, s2);
    kern_query<<<NQRY, 256, 0, stream>>>(feat, temp, table, supT, s2, out);
    kern_loss<<<(NQRY + 255)/256, 256, 0, stream>>>(out, label, loss_slot);
}

// Round 7
// 351.198 us; speedup vs baseline: 1.0019x; 1.0019x over previous
//
#include <hip/hip_runtime.h>
#include <math.h>

// Problem constants (from reference)
#define NWAY   10
#define DIMD   64
#define HWN    49           // H*W = 7*7
#define NSUP   800          // N_WAY*K_SHOT*PRJ
#define NQRY   16000        // N_WAY*Q_QUERY*PRJ
#define NTRI   2080         // 64*65/2
#define FEAT_PER (DIMD*HWN) // 3136 floats per sample
#define STP    12           // transposed support row stride (floats): 48 B

typedef __attribute__((ext_vector_type(8))) short bf16x8;
typedef __attribute__((ext_vector_type(4))) float f32x4;

// LDS: hl (staging) -> dcov (centered matrix) -> part (reduction), overlaid.
// Pads removed; bank spread via 16B-chunk XOR swizzle (chunk ^= row&7).
// sizeof ~= 16976 B (was 19456) -> 7-8 blocks/CU resident (was ~6).
struct __align__(16) BDCShared {
    union {
        unsigned short hl[2*DIMD*64];    // 16384 B: H[64][64], L[64][64]
        float dcov[DIMD*64];             // 16384 B: CENTERED dcov, swizzled
        float part[256*12];              // 12288 B: reduction partials
    } u;
    float dg[DIMD];
    float rm[DIMD];
    float w4[4];            // per-wave partial for tm
    float red[16];          // final 11 sums
};

// Map linear triu index k -> (i,j), j>=i, row-major triu of 64x64 (init only).
__device__ __forceinline__ void k2ij(int k, int& io, int& jo) {
    int ii = (int)floorf((129.0f - sqrtf(16641.0f - 8.0f*(float)k)) * 0.5f);
    int off = ii*(129-ii)/2;
    if (off > k) { --ii; off = ii*(129-ii)/2; }
    else {
        int off2 = (ii+1)*(128-ii)/2;
        if (off2 <= k) { ii += 1; off = off2; }
    }
    io = ii;
    jo = ii + (k - off);
}

// HW packed bf16 convert (RNE): r.lo16 = bf16(a), r.hi16 = bf16(b)
__device__ __forceinline__ unsigned cvt_pk_bf16(float a, float b) {
    unsigned r;
    asm("v_cvt_pk_bf16_f32 %0, %1, %2" : "=v"(r) : "v"(a), "v"(b));
    return r;
}

// bf16 staging: row-major [64][64] shorts, swizzled in 8-short (16B) chunks:
// element e of row r lives in chunk ((e>>3) ^ (r&7)).
#define HL_ADDR(BASE, row, e) \
    ((BASE) + (row)*64 + (((((e) >> 3) ^ ((row) & 7))) << 3))

// MFMA-based BDC. On return:
//   sm.u.dcov holds the full CENTERED dcov matrix (swizzled layout)
//   vJ[r] = centered value at (i = 16wv+4qd+r, j = 16J+c15) (register copy)
//   returns tm. Block = 256 threads = 4 waves.
__device__ __forceinline__ float bdc_compute(const float* __restrict__ feat,
                                             float et, int sample, BDCShared& sm,
                                             f32x4& v0, f32x4& v1, f32x4& v2,
                                             f32x4& v3) {
    const int tid = threadIdx.x;
    unsigned short* Hh = sm.u.hl;
    unsigned short* Lh = sm.u.hl + DIMD*64;

    // ---- Stage: row-mapped. Thread owns (row d, quarter hq): 16 contiguous k.
    {
        const int d = tid & 63, hq = tid >> 6;       // hq is wave-uniform
        const float* rowp = feat + (size_t)sample * FEAT_PER + d*HWN + hq*16;
        float x[16];
        if (hq < 3) {
            #pragma unroll
            for (int i = 0; i < 16; ++i) x[i] = rowp[i];
        } else {
            x[0] = rowp[0];                          // k = 48
            #pragma unroll
            for (int i = 1; i < 16; ++i) x[i] = 0.0f;
        }
        unsigned hp[8], lp[8];
        #pragma unroll
        for (int i = 0; i < 8; ++i) {
            unsigned h = cvt_pk_bf16(x[2*i], x[2*i+1]);
            float h0 = __uint_as_float(h << 16);
            float h1 = __uint_as_float(h & 0xffff0000u);
            hp[i] = h;
            lp[i] = cvt_pk_bf16(x[2*i] - h0, x[2*i+1] - h1);
        }
        // two 16B chunks per thread per plane, XOR-swizzled
        const int sw0 = (hq*2)     ^ (d & 7);
        const int sw1 = (hq*2 + 1) ^ (d & 7);
        *(uint4*)&Hh[d*64 + sw0*8] = make_uint4(hp[0], hp[1], hp[2], hp[3]);
        *(uint4*)&Hh[d*64 + sw1*8] = make_uint4(hp[4], hp[5], hp[6], hp[7]);
        *(uint4*)&Lh[d*64 + sw0*8] = make_uint4(lp[0], lp[1], lp[2], lp[3]);
        *(uint4*)&Lh[d*64 + sw1*8] = make_uint4(lp[4], lp[5], lp[6], lp[7]);
    }
    __syncthreads();

    // ---- Gram via MFMA 16x16x32 bf16. Wave w owns G rows 16w..16w+15.
    const int wv = tid >> 6, lane = tid & 63;
    const int qd = lane >> 4, c15 = lane & 15;
    const int rA = 16*wv + c15;
    bf16x8 AH0 = *(const bf16x8*)HL_ADDR(Hh, rA, qd*8);
    bf16x8 AH1 = *(const bf16x8*)HL_ADDR(Hh, rA, qd*8 + 32);
    bf16x8 AL0 = *(const bf16x8*)HL_ADDR(Lh, rA, qd*8);
    bf16x8 AL1 = *(const bf16x8*)HL_ADDR(Lh, rA, qd*8 + 32);

    f32x4 acc[4];                      // constant-indexed only (unrolled)
    #pragma unroll
    for (int J = 0; J < 4; ++J) {
        const int rB = 16*J + c15;
        bf16x8 BH0 = *(const bf16x8*)HL_ADDR(Hh, rB, qd*8);
        bf16x8 BH1 = *(const bf16x8*)HL_ADDR(Hh, rB, qd*8 + 32);
        bf16x8 BL0 = *(const bf16x8*)HL_ADDR(Lh, rB, qd*8);
        bf16x8 BL1 = *(const bf16x8*)HL_ADDR(Lh, rB, qd*8 + 32);
        f32x4 a = {0.f, 0.f, 0.f, 0.f};
        a = __builtin_amdgcn_mfma_f32_16x16x32_bf16(AH0, BH0, a, 0, 0, 0);
        a = __builtin_amdgcn_mfma_f32_16x16x32_bf16(AH1, BH1, a, 0, 0, 0);
        a = __builtin_amdgcn_mfma_f32_16x16x32_bf16(AL0, BH0, a, 0, 0, 0);
        a = __builtin_amdgcn_mfma_f32_16x16x32_bf16(AL1, BH1, a, 0, 0, 0);
        a = __builtin_amdgcn_mfma_f32_16x16x32_bf16(AH0, BL0, a, 0, 0, 0);
        a = __builtin_amdgcn_mfma_f32_16x16x32_bf16(AH1, BL1, a, 0, 0, 0);
        acc[J] = a;
    }

    // ---- dg from G diagonal (tile J == wv). C/D: col=lane&15, row=quad*4+reg.
    #pragma unroll
    for (int J = 0; J < 4; ++J) {
        if (J == wv) {
            #pragma unroll
            for (int r = 0; r < 4; ++r)
                if (c15 == 4*qd + r) sm.dg[16*wv + c15] = acc[J][r];
        }
    }
    __syncthreads();   // dg visible; all frag reads of u.hl done

    // ---- sqrt'd dcov in registers (v0..v3, uncentered) + in-register row sums
    f32x4 dgi = *(const f32x4*)&sm.dg[16*wv + 4*qd];
    float rs0 = 0.f, rs1 = 0.f, rs2 = 0.f, rs3 = 0.f;
#define DCOV_J(J, VJ)                                                          \
    {   float dgj = sm.dg[16*(J) + c15];                                       \
        _Pragma("unroll")                                                      \
        for (int r = 0; r < 4; ++r) {                                          \
            float t2 = fmaf(-2.0f, acc[J][r], dgi[r] + dgj);                   \
            t2 = fmaxf(t2, 0.0f);                                              \
            VJ[r] = __builtin_amdgcn_sqrtf(fmaf(et, t2, 1e-5f));               \
        }                                                                      \
        rs0 += VJ[0]; rs1 += VJ[1]; rs2 += VJ[2]; rs3 += VJ[3]; }
    DCOV_J(0, v0)
    DCOV_J(1, v1)
    DCOV_J(2, v2)
    DCOV_J(3, v3)
#undef DCOV_J

    // butterfly over the 16 c15-lanes: all lanes end with full row sums
    #pragma unroll
    for (int off = 1; off < 16; off <<= 1) {
        rs0 += __shfl_xor(rs0, off, 64);
        rs1 += __shfl_xor(rs1, off, 64);
        rs2 += __shfl_xor(rs2, off, 64);
        rs3 += __shfl_xor(rs3, off, 64);
    }
    if (c15 == 0) {
        f32x4 rmv = {rs0*(1.0f/64.0f), rs1*(1.0f/64.0f),
                     rs2*(1.0f/64.0f), rs3*(1.0f/64.0f)};
        *(f32x4*)&sm.rm[16*wv + 4*qd] = rmv;
    }
    float tt = (rs0 + rs1) + (rs2 + rs3);
    tt += __shfl_xor(tt, 16, 64);
    tt += __shfl_xor(tt, 32, 64);
    if (lane == 0) sm.w4[wv] = tt;
    __syncthreads();   // rm + w4 visible
    float tm = (sm.w4[0] + sm.w4[1] + sm.w4[2] + sm.w4[3]) * (1.0f/4096.0f);

    // ---- center in registers, write CENTERED matrix to LDS at swizzled
    // transposed position [j][iB..iB+3] (valid by symmetry): float-chunk
    // c = iB>>2 = 4wv+qd, swizzled c^(j&7). Tail reads via pre-swizzled table.
    const float rmi0 = rs0*(1.0f/64.0f), rmi1 = rs1*(1.0f/64.0f),
                rmi2 = rs2*(1.0f/64.0f), rmi3 = rs3*(1.0f/64.0f);
    float* dcovf = sm.u.dcov;
    const int cch = 4*wv + qd;         // 16B chunk index (0..15)
#define CENTER_J(J, VJ)                                                        \
    {   int j16 = 16*(J) + c15;                                                \
        float rmj = sm.rm[j16] - tm;                                           \
        VJ[0] = VJ[0] - rmi0 - rmj;                                            \
        VJ[1] = VJ[1] - rmi1 - rmj;                                            \
        VJ[2] = VJ[2] - rmi2 - rmj;                                            \
        VJ[3] = VJ[3] - rmi3 - rmj;                                            \
        *(f32x4*)&dcovf[j16*64 + ((cch ^ (j16 & 7)) << 2)] = VJ; }
    CENTER_J(0, v0)
    CENTER_J(1, v1)
    CENTER_J(2, v2)
    CENTER_J(3, v3)
#undef CENTER_J
    __syncthreads();   // centered dcov visible
    return tm;
}

// init: triu table (swizzled_faddr<<16 | i<<8 | j), zero s2 + loss slot.
// value(ii,jj) lives at dcov row jj, float-col ii, chunk-swizzled.
__global__ void kern_init(unsigned* __restrict__ table,
                          float* __restrict__ s2,
                          float* __restrict__ loss_slot) {
    int i = blockIdx.x * 256 + threadIdx.x;
    if (i < NTRI) {
        int ii, jj; k2ij(i, ii, jj);
        unsigned faddr = (unsigned)(jj*64 + ((((ii >> 2) ^ (jj & 7)) << 2) | (ii & 3)));
        table[i] = (faddr << 16) | ((unsigned)ii << 8) | (unsigned)jj;
    }
    if (i < NWAY) s2[i] = 0.0f;
    if (i == 0) loss_slot[0] = 0.0f;
}

// Support: BDC -> centered triu vector scattered to global from registers.
__global__ __launch_bounds__(256, 8) void kern_support(const float* __restrict__ feat,
                                                       const float* __restrict__ temp,
                                                       float* __restrict__ tvout) {
    __shared__ BDCShared sm;
    float et = __expf(temp[0]);
    int s = blockIdx.x;                 // 0..799
    f32x4 v0, v1, v2, v3;
    bdc_compute(feat, et, s, sm, v0, v1, v2, v3);

    const int tid = threadIdx.x;
    const int wv = tid >> 6, lane = tid & 63;
    const int qd = lane >> 4, c15 = lane & 15;
    const int iB = 16*wv + 4*qd;
    float* dst = tvout + (size_t)s * NTRI;
#define SUP_J(J, VJ)                                                           \
    {   int j = 16*(J) + c15;                                                  \
        _Pragma("unroll")                                                      \
        for (int r = 0; r < 4; ++r) {                                          \
            int i = iB + r;                                                    \
            if (j >= i) dst[i*(129 - i)/2 + (j - i)] = VJ[r]; } }
    SUP_J(0, v0)
    SUP_J(1, v1)
    SUP_J(2, v2)
    SUP_J(3, v3)
#undef SUP_J
}

// Deterministic reduce: prototype means (transposed [k][12]) + s2.
// Grid = NWAY * 9 blocks; block (m, kc) handles k in [kc*256, kc*256+256).
__global__ __launch_bounds__(256) void kern_reduce(const float* __restrict__ tv,
                                                   const unsigned* __restrict__ table,
                                                   float* __restrict__ supT,
                                                   float* __restrict__ s2) {
    __shared__ float red[4];
    int m = blockIdx.x / 9, kc = blockIdx.x % 9;
    int k = kc*256 + threadIdx.x;
    float S = 0.0f;
    if (k < NTRI) {
        const float* p = tv + (size_t)(80*m) * NTRI + k;
        float a0 = 0.f, a1 = 0.f, a2 = 0.f, a3 = 0.f;
        for (int s4 = 0; s4 < 80; s4 += 4) {
            a0 += p[(size_t)(s4+0)*NTRI];
            a1 += p[(size_t)(s4+1)*NTRI];
            a2 += p[(size_t)(s4+2)*NTRI];
            a3 += p[(size_t)(s4+3)*NTRI];
        }
        S = ((a0+a1)+(a2+a3)) * (1.0f/80.0f);
        supT[k*STP + m] = S;
    }
    float ps = S * S;   // 0 for k >= NTRI
    int lane = threadIdx.x & 63, wv = threadIdx.x >> 6;
    #pragma unroll
    for (int off = 32; off > 0; off >>= 1) ps += __shfl_xor(ps, off, 64);
    if (lane == 0) red[wv] = ps;
    __syncthreads();
    if (threadIdx.x == 0) atomicAdd(&s2[m], red[0]+red[1]+red[2]+red[3]);
}

// Query: BDC (centered, swizzled LDS) -> triu-table loop -> transpose reduce.
__global__ __launch_bounds__(256, 8) void kern_query(const float* __restrict__ feat,
                                                     const float* __restrict__ temp,
                                                     const unsigned* __restrict__ table,
                                                     const float* __restrict__ supT,
                                                     const float* __restrict__ s2,
                                                     float* __restrict__ out) {
    __shared__ BDCShared sm;
    float et = __expf(temp[0]);
    int qn = blockIdx.x;                // 0..15999
    f32x4 v0, v1, v2, v3;
    bdc_compute(feat, et, NSUP + qn, sm, v0, v1, v2, v3);

    const int tid = threadIdx.x;
    float qq = 0.0f;
    float cr[NWAY];                    // constant-indexed only (unrolled)
    #pragma unroll
    for (int m = 0; m < NWAY; ++m) cr[m] = 0.0f;

    const float* dcov = sm.u.dcov;
    for (int k = tid; k < NTRI; k += 256) {
        unsigned t = table[k];
        float v = dcov[t >> 16];       // centered, pre-swizzled address
        qq = fmaf(v, v, qq);
        const float4* sp = (const float4*)(supT + (size_t)k * STP);
        float4 sa = sp[0], sb = sp[1], sc = sp[2];   // cols 10,11 pad
        cr[0] = fmaf(v, sa.x, cr[0]);
        cr[1] = fmaf(v, sa.y, cr[1]);
        cr[2] = fmaf(v, sa.z, cr[2]);
        cr[3] = fmaf(v, sa.w, cr[3]);
        cr[4] = fmaf(v, sb.x, cr[4]);
        cr[5] = fmaf(v, sb.y, cr[5]);
        cr[6] = fmaf(v, sb.z, cr[6]);
        cr[7] = fmaf(v, sb.w, cr[7]);
        cr[8] = fmaf(v, sc.x, cr[8]);
        cr[9] = fmaf(v, sc.y, cr[9]);
    }
    __syncthreads();                   // all dcov reads done -> part overlay safe

    // LDS transpose reduce: 3x b128 write/thread, 176 threads gather, 4-step shfl
    float* part = sm.u.part;
    f32x4 p0 = {cr[0], cr[1], cr[2], cr[3]};
    f32x4 p1 = {cr[4], cr[5], cr[6], cr[7]};
    f32x4 p2 = {cr[8], cr[9], qq, 0.0f};
    *(f32x4*)&part[tid*12 + 0] = p0;
    *(f32x4*)&part[tid*12 + 4] = p1;
    *(f32x4*)&part[tid*12 + 8] = p2;
    __syncthreads();
    if (tid < 176) {
        int m = tid >> 4, g = tid & 15;
        float s = 0.0f;
        #pragma unroll
        for (int t = 0; t < 16; ++t) s += part[(g + 16*t)*12 + m];
        #pragma unroll
        for (int off = 1; off < 16; off <<= 1) s += __shfl_xor(s, off, 64);
        if (g == 0) sm.red[m] = s;
    }
    __syncthreads();
    if (tid < NWAY)
        out[(size_t)qn * NWAY + tid] = -(sm.red[10] + s2[tid] - 2.0f*sm.red[tid]);
}

// Softmax NLL partials: one atomicAdd per block.
__global__ __launch_bounds__(256) void kern_loss(const float* __restrict__ score,
                                                 const int* __restrict__ label,
                                                 float* __restrict__ loss_out) {
    __shared__ float red[4];
    int n = blockIdx.x * 256 + threadIdx.x;
    float lsum = 0.0f;
    if (n < NQRY) {
        const float* srow = score + (size_t)n * NWAY;
        float s[NWAY];
        float mx = -1e30f;
        #pragma unroll
        for (int m = 0; m < NWAY; ++m) { s[m] = srow[m]; mx = fmaxf(mx, s[m]); }
        float se = 0.0f;
        #pragma unroll
        for (int m = 0; m < NWAY; ++m) se += __expf(s[m] - mx);
        float lse = mx + __logf(se);
        lsum = lse - s[label[n]];
    }
    int lane = threadIdx.x & 63, wv = threadIdx.x >> 6;
    #pragma unroll
    for (int off = 32; off > 0; off >>= 1) lsum += __shfl_xor(lsum, off, 64);
    if (lane == 0) red[wv] = lsum;
    __syncthreads();
    if (threadIdx.x == 0)
        atomicAdd(loss_out, (red[0] + red[1] + red[2] + red[3]) * (1.0f / (float)NQRY));
}

extern "C" void kernel_launch(void* const* d_in, const int* in_sizes, int n_in,
                              void* d_out, int out_size, void* d_ws, size_t ws_size,
                              hipStream_t stream) {
    (void)in_sizes; (void)n_in; (void)out_size; (void)ws_size;
    const float* feat = (const float*)d_in[0];
    const float* temp = (const float*)d_in[1];
    const int*   label = (const int*)d_in[2];
    float* out = (float*)d_out;

    // workspace layout (~6.8 MB):
    float*    tv    = (float*)d_ws;                  // 800*2080 f = 6.656 MB
    float*    supT  = tv + (size_t)NSUP * NTRI;      // 2080*12 f (transposed+pad)
    float*    s2    = supT + NTRI*STP;               // 10 f (+pad)
    unsigned* table = (unsigned*)(s2 + 16);          // 2080 u32
    float* loss_slot = out + (size_t)NQRY * NWAY;

    kern_init<<<(NTRI + 255)/256, 256, 0, stream>>>(table, s2, loss_slot);
    kern_support<<<NSUP, 256, 0, stream>>>(feat, temp, tv);
    kern_reduce<<<NWAY*9, 256, 0, stream>>>(tv, table, supT, s2);
    kern_query<<<NQRY, 256, 0, stream>>>(feat, temp, table, supT, s2, out);
    kern_loss<<<(NQRY + 255)/256, 256, 0, stream>>>(out, label, loss_slot);
}

// Round 8
// 337.356 us; speedup vs baseline: 1.0430x; 1.0410x over previous
//
#include <hip/hip_runtime.h>
#include <math.h>

// Problem constants (from reference)
#define NWAY   10
#define DIMD   64
#define HWN    49           // H*W = 7*7
#define NSUP   800          // N_WAY*K_SHOT*PRJ
#define NQRY   16000        // N_WAY*Q_QUERY*PRJ
#define NTRI   2080         // 64*65/2
#define FEAT_PER (DIMD*HWN) // 3136 floats per sample
#define STP    12           // transposed support row stride (floats): 48 B

typedef __attribute__((ext_vector_type(8))) short bf16x8;
typedef __attribute__((ext_vector_type(4))) float f32x4;

// ---- single-query shared block (kern_support) -------------------------------
struct __align__(16) BDCShared {
    union {
        unsigned short hl[2*DIMD*64];    // 16384 B: H[64][64], L[64][64]
        float dcov[DIMD*64];             // 16384 B: CENTERED dcov, swizzled
        float part[256*12];              // 12288 B: reduction partials
    } u;
    float dg[DIMD];
    float rm[DIMD];
    float w4[4];
    float red[16];
};

// ---- dual-query shared block (kern_query: 2 queries per block) --------------
// Two independent 16 KB regions (staging->dcov->part overlays) + bookkeeping.
// sizeof ~= 33952 B -> 4 blocks/CU (135.8 KB of 160 KB).
struct __align__(16) BDC2Shared {
    union Reg {
        unsigned short hl[2*DIMD*64];    // 16384 B
        float dcov[DIMD*64];             // 16384 B
        float part[256*12];              // 12288 B
    };
    Reg r0;
    Reg r1;
    float dg0[DIMD], dg1[DIMD];
    float rm0[DIMD], rm1[DIMD];
    float w40[4], w41[4];
    float red0[16], red1[16];
};

// Map linear triu index k -> (i,j), j>=i, row-major triu of 64x64 (init only).
__device__ __forceinline__ void k2ij(int k, int& io, int& jo) {
    int ii = (int)floorf((129.0f - sqrtf(16641.0f - 8.0f*(float)k)) * 0.5f);
    int off = ii*(129-ii)/2;
    if (off > k) { --ii; off = ii*(129-ii)/2; }
    else {
        int off2 = (ii+1)*(128-ii)/2;
        if (off2 <= k) { ii += 1; off = off2; }
    }
    io = ii;
    jo = ii + (k - off);
}

// HW packed bf16 convert (RNE): r.lo16 = bf16(a), r.hi16 = bf16(b)
__device__ __forceinline__ unsigned cvt_pk_bf16(float a, float b) {
    unsigned r;
    asm("v_cvt_pk_bf16_f32 %0, %1, %2" : "=v"(r) : "v"(a), "v"(b));
    return r;
}

// bf16 staging: row-major [64][64] shorts, swizzled in 8-short (16B) chunks:
// element e of row r lives in chunk ((e>>3) ^ (r&7)).
#define HL_ADDR(BASE, row, e) \
    ((BASE) + (row)*64 + (((((e) >> 3) ^ ((row) & 7))) << 3))

// ============================================================================
// Phase macros shared by the 1-query and 2-query kernels. All indexing is
// compile-time (rule #20); wave geometry vars (d,hq,sw0,sw1,wv,lane,qd,c15,rA)
// must be in scope.
// ============================================================================

// Stage one sample into region HLBASE (H plane then L plane).
#define STAGE_Q(HLBASE, SAMPLE)                                                \
    {   const float* rowp = feat + (size_t)(SAMPLE)*FEAT_PER + d*HWN + hq*16;  \
        float x[16];                                                           \
        if (hq < 3) {                                                          \
            _Pragma("unroll")                                                  \
            for (int i = 0; i < 16; ++i) x[i] = rowp[i];                       \
        } else {                                                               \
            x[0] = rowp[0];                                                    \
            _Pragma("unroll")                                                  \
            for (int i = 1; i < 16; ++i) x[i] = 0.0f;                          \
        }                                                                      \
        unsigned hp[8], lp[8];                                                 \
        _Pragma("unroll")                                                      \
        for (int i = 0; i < 8; ++i) {                                          \
            unsigned h = cvt_pk_bf16(x[2*i], x[2*i+1]);                        \
            float h0 = __uint_as_float(h << 16);                               \
            float h1 = __uint_as_float(h & 0xffff0000u);                       \
            hp[i] = h;                                                         \
            lp[i] = cvt_pk_bf16(x[2*i] - h0, x[2*i+1] - h1);                   \
        }                                                                      \
        unsigned short* Hq = (HLBASE);                                         \
        unsigned short* Lq = (HLBASE) + DIMD*64;                               \
        *(uint4*)&Hq[d*64 + sw0*8] = make_uint4(hp[0], hp[1], hp[2], hp[3]);   \
        *(uint4*)&Hq[d*64 + sw1*8] = make_uint4(hp[4], hp[5], hp[6], hp[7]);   \
        *(uint4*)&Lq[d*64 + sw0*8] = make_uint4(lp[0], lp[1], lp[2], lp[3]);   \
        *(uint4*)&Lq[d*64 + sw1*8] = make_uint4(lp[4], lp[5], lp[6], lp[7]); }

// Gram of one region into ACC[0..3] (f32x4[4], constant-indexed).
#define GRAM_Q(HLBASE, ACC)                                                    \
    {   unsigned short* Hq = (HLBASE);                                         \
        unsigned short* Lq = (HLBASE) + DIMD*64;                               \
        bf16x8 AH0 = *(const bf16x8*)HL_ADDR(Hq, rA, qd*8);                    \
        bf16x8 AH1 = *(const bf16x8*)HL_ADDR(Hq, rA, qd*8 + 32);               \
        bf16x8 AL0 = *(const bf16x8*)HL_ADDR(Lq, rA, qd*8);                    \
        bf16x8 AL1 = *(const bf16x8*)HL_ADDR(Lq, rA, qd*8 + 32);               \
        _Pragma("unroll")                                                      \
        for (int J = 0; J < 4; ++J) {                                          \
            const int rB = 16*J + c15;                                         \
            bf16x8 BH0 = *(const bf16x8*)HL_ADDR(Hq, rB, qd*8);                \
            bf16x8 BH1 = *(const bf16x8*)HL_ADDR(Hq, rB, qd*8 + 32);           \
            bf16x8 BL0 = *(const bf16x8*)HL_ADDR(Lq, rB, qd*8);                \
            bf16x8 BL1 = *(const bf16x8*)HL_ADDR(Lq, rB, qd*8 + 32);           \
            f32x4 a = {0.f, 0.f, 0.f, 0.f};                                    \
            a = __builtin_amdgcn_mfma_f32_16x16x32_bf16(AH0, BH0, a, 0, 0, 0); \
            a = __builtin_amdgcn_mfma_f32_16x16x32_bf16(AH1, BH1, a, 0, 0, 0); \
            a = __builtin_amdgcn_mfma_f32_16x16x32_bf16(AL0, BH0, a, 0, 0, 0); \
            a = __builtin_amdgcn_mfma_f32_16x16x32_bf16(AL1, BH1, a, 0, 0, 0); \
            a = __builtin_amdgcn_mfma_f32_16x16x32_bf16(AH0, BL0, a, 0, 0, 0); \
            a = __builtin_amdgcn_mfma_f32_16x16x32_bf16(AH1, BL1, a, 0, 0, 0); \
            ACC[J] = a;                                                        \
        } }

// sqrt'd dcov for tile J of one query: VJ out, rowsums accumulated.
#define DCOV_J(J, VJ, ACC, DGARR, DGI, RS0, RS1, RS2, RS3)                     \
    {   float dgj = (DGARR)[16*(J) + c15];                                     \
        _Pragma("unroll")                                                      \
        for (int r = 0; r < 4; ++r) {                                          \
            float t2 = fmaf(-2.0f, ACC[J][r], (DGI)[r] + dgj);                 \
            t2 = fmaxf(t2, 0.0f);                                              \
            VJ[r] = __builtin_amdgcn_sqrtf(fmaf(et, t2, 1e-5f));               \
        }                                                                      \
        RS0 += VJ[0]; RS1 += VJ[1]; RS2 += VJ[2]; RS3 += VJ[3]; }

// center + swizzled transposed LDS write for tile J of one query.
#define CENTER_J(J, VJ, RMARR, DCOVF, TM, RMI0, RMI1, RMI2, RMI3)              \
    {   int j16 = 16*(J) + c15;                                                \
        float rmj = (RMARR)[j16] - (TM);                                       \
        VJ[0] = VJ[0] - (RMI0) - rmj;                                          \
        VJ[1] = VJ[1] - (RMI1) - rmj;                                          \
        VJ[2] = VJ[2] - (RMI2) - rmj;                                          \
        VJ[3] = VJ[3] - (RMI3) - rmj;                                          \
        *(f32x4*)&(DCOVF)[j16*64 + ((cch ^ (j16 & 7)) << 2)] = VJ; }

// ============================================================================
// Single-query BDC (kern_support) — identical to round-7 version.
// ============================================================================
__device__ __forceinline__ float bdc_compute(const float* __restrict__ feat,
                                             float et, int sample, BDCShared& sm,
                                             f32x4& v0, f32x4& v1, f32x4& v2,
                                             f32x4& v3) {
    const int tid = threadIdx.x;
    const int d = tid & 63, hq = tid >> 6;
    const int sw0 = (hq*2) ^ (d & 7);
    const int sw1 = (hq*2 + 1) ^ (d & 7);
    STAGE_Q(sm.u.hl, sample)
    __syncthreads();

    const int wv = tid >> 6, lane = tid & 63;
    const int qd = lane >> 4, c15 = lane & 15;
    const int rA = 16*wv + c15;
    f32x4 acc[4];
    GRAM_Q(sm.u.hl, acc)

    #pragma unroll
    for (int J = 0; J < 4; ++J) {
        if (J == wv) {
            #pragma unroll
            for (int r = 0; r < 4; ++r)
                if (c15 == 4*qd + r) sm.dg[16*wv + c15] = acc[J][r];
        }
    }
    __syncthreads();

    f32x4 dgi = *(const f32x4*)&sm.dg[16*wv + 4*qd];
    float rs0 = 0.f, rs1 = 0.f, rs2 = 0.f, rs3 = 0.f;
    DCOV_J(0, v0, acc, sm.dg, dgi, rs0, rs1, rs2, rs3)
    DCOV_J(1, v1, acc, sm.dg, dgi, rs0, rs1, rs2, rs3)
    DCOV_J(2, v2, acc, sm.dg, dgi, rs0, rs1, rs2, rs3)
    DCOV_J(3, v3, acc, sm.dg, dgi, rs0, rs1, rs2, rs3)

    #pragma unroll
    for (int off = 1; off < 16; off <<= 1) {
        rs0 += __shfl_xor(rs0, off, 64);
        rs1 += __shfl_xor(rs1, off, 64);
        rs2 += __shfl_xor(rs2, off, 64);
        rs3 += __shfl_xor(rs3, off, 64);
    }
    if (c15 == 0) {
        f32x4 rmv = {rs0*(1.0f/64.0f), rs1*(1.0f/64.0f),
                     rs2*(1.0f/64.0f), rs3*(1.0f/64.0f)};
        *(f32x4*)&sm.rm[16*wv + 4*qd] = rmv;
    }
    float tt = (rs0 + rs1) + (rs2 + rs3);
    tt += __shfl_xor(tt, 16, 64);
    tt += __shfl_xor(tt, 32, 64);
    if (lane == 0) sm.w4[wv] = tt;
    __syncthreads();
    float tm = (sm.w4[0] + sm.w4[1] + sm.w4[2] + sm.w4[3]) * (1.0f/4096.0f);

    const float rmi0 = rs0*(1.0f/64.0f), rmi1 = rs1*(1.0f/64.0f),
                rmi2 = rs2*(1.0f/64.0f), rmi3 = rs3*(1.0f/64.0f);
    float* dcovf = sm.u.dcov;
    const int cch = 4*wv + qd;
    CENTER_J(0, v0, sm.rm, dcovf, tm, rmi0, rmi1, rmi2, rmi3)
    CENTER_J(1, v1, sm.rm, dcovf, tm, rmi0, rmi1, rmi2, rmi3)
    CENTER_J(2, v2, sm.rm, dcovf, tm, rmi0, rmi1, rmi2, rmi3)
    CENTER_J(3, v3, sm.rm, dcovf, tm, rmi0, rmi1, rmi2, rmi3)
    __syncthreads();
    return tm;
}

// init: triu table (swizzled_faddr<<16 | i<<8 | j), zero s2 + loss slot.
__global__ void kern_init(unsigned* __restrict__ table,
                          float* __restrict__ s2,
                          float* __restrict__ loss_slot) {
    int i = blockIdx.x * 256 + threadIdx.x;
    if (i < NTRI) {
        int ii, jj; k2ij(i, ii, jj);
        unsigned faddr = (unsigned)(jj*64 + ((((ii >> 2) ^ (jj & 7)) << 2) | (ii & 3)));
        table[i] = (faddr << 16) | ((unsigned)ii << 8) | (unsigned)jj;
    }
    if (i < NWAY) s2[i] = 0.0f;
    if (i == 0) loss_slot[0] = 0.0f;
}

// Support: BDC -> centered triu vector scattered to global from registers.
__global__ __launch_bounds__(256, 8) void kern_support(const float* __restrict__ feat,
                                                       const float* __restrict__ temp,
                                                       float* __restrict__ tvout) {
    __shared__ BDCShared sm;
    float et = __expf(temp[0]);
    int s = blockIdx.x;                 // 0..799
    f32x4 v0, v1, v2, v3;
    bdc_compute(feat, et, s, sm, v0, v1, v2, v3);

    const int tid = threadIdx.x;
    const int wv = tid >> 6, lane = tid & 63;
    const int qd = lane >> 4, c15 = lane & 15;
    const int iB = 16*wv + 4*qd;
    float* dst = tvout + (size_t)s * NTRI;
#define SUP_J(J, VJ)                                                           \
    {   int j = 16*(J) + c15;                                                  \
        _Pragma("unroll")                                                      \
        for (int r = 0; r < 4; ++r) {                                          \
            int i = iB + r;                                                    \
            if (j >= i) dst[i*(129 - i)/2 + (j - i)] = VJ[r]; } }
    SUP_J(0, v0)
    SUP_J(1, v1)
    SUP_J(2, v2)
    SUP_J(3, v3)
#undef SUP_J
}

// Deterministic reduce: prototype means (transposed [k][12]) + s2.
__global__ __launch_bounds__(256) void kern_reduce(const float* __restrict__ tv,
                                                   const unsigned* __restrict__ table,
                                                   float* __restrict__ supT,
                                                   float* __restrict__ s2) {
    __shared__ float red[4];
    int m = blockIdx.x / 9, kc = blockIdx.x % 9;
    int k = kc*256 + threadIdx.x;
    float S = 0.0f;
    if (k < NTRI) {
        const float* p = tv + (size_t)(80*m) * NTRI + k;
        float a0 = 0.f, a1 = 0.f, a2 = 0.f, a3 = 0.f;
        for (int s4 = 0; s4 < 80; s4 += 4) {
            a0 += p[(size_t)(s4+0)*NTRI];
            a1 += p[(size_t)(s4+1)*NTRI];
            a2 += p[(size_t)(s4+2)*NTRI];
            a3 += p[(size_t)(s4+3)*NTRI];
        }
        S = ((a0+a1)+(a2+a3)) * (1.0f/80.0f);
        supT[k*STP + m] = S;
    }
    float ps = S * S;   // 0 for k >= NTRI
    int lane = threadIdx.x & 63, wv = threadIdx.x >> 6;
    #pragma unroll
    for (int off = 32; off > 0; off >>= 1) ps += __shfl_xor(ps, off, 64);
    if (lane == 0) red[wv] = ps;
    __syncthreads();
    if (threadIdx.x == 0) atomicAdd(&s2[m], red[0]+red[1]+red[2]+red[3]);
}

// ============================================================================
// Query: TWO queries per block. Every barrier-separated phase carries both
// queries' independent work (2x ILP); supT stream amortized over 2 queries.
// ============================================================================
__global__ __launch_bounds__(256, 4) void kern_query(const float* __restrict__ feat,
                                                     const float* __restrict__ temp,
                                                     const unsigned* __restrict__ table,
                                                     const float* __restrict__ supT,
                                                     const float* __restrict__ s2,
                                                     float* __restrict__ out) {
    __shared__ BDC2Shared sm;
    float et = __expf(temp[0]);
    const int qn0 = blockIdx.x * 2;
    const int qn1 = qn0 + 1;
    const int tid = threadIdx.x;

    // ---- Stage both samples (all 8 global b128 loads issue before waits)
    {
        const int d = tid & 63, hq = tid >> 6;
        const int sw0 = (hq*2) ^ (d & 7);
        const int sw1 = (hq*2 + 1) ^ (d & 7);
        STAGE_Q(sm.r0.hl, NSUP + qn0)
        STAGE_Q(sm.r1.hl, NSUP + qn1)
    }
    __syncthreads();

    // ---- Gram both (48 MFMAs, independent chains)
    const int wv = tid >> 6, lane = tid & 63;
    const int qd = lane >> 4, c15 = lane & 15;
    const int rA = 16*wv + c15;
    f32x4 acc0[4], acc1[4];
    GRAM_Q(sm.r0.hl, acc0)
    GRAM_Q(sm.r1.hl, acc1)

    #pragma unroll
    for (int J = 0; J < 4; ++J) {
        if (J == wv) {
            #pragma unroll
            for (int r = 0; r < 4; ++r)
                if (c15 == 4*qd + r) {
                    sm.dg0[16*wv + c15] = acc0[J][r];
                    sm.dg1[16*wv + c15] = acc1[J][r];
                }
        }
    }
    __syncthreads();

    // ---- dcov both + in-register row sums (interleaved sqrt/shfl chains)
    f32x4 dgi0 = *(const f32x4*)&sm.dg0[16*wv + 4*qd];
    f32x4 dgi1 = *(const f32x4*)&sm.dg1[16*wv + 4*qd];
    f32x4 v00, v01, v02, v03, v10, v11, v12, v13;
    float rs00 = 0.f, rs01 = 0.f, rs02 = 0.f, rs03 = 0.f;
    float rs10 = 0.f, rs11 = 0.f, rs12 = 0.f, rs13 = 0.f;
    DCOV_J(0, v00, acc0, sm.dg0, dgi0, rs00, rs01, rs02, rs03)
    DCOV_J(1, v01, acc0, sm.dg0, dgi0, rs00, rs01, rs02, rs03)
    DCOV_J(2, v02, acc0, sm.dg0, dgi0, rs00, rs01, rs02, rs03)
    DCOV_J(3, v03, acc0, sm.dg0, dgi0, rs00, rs01, rs02, rs03)
    DCOV_J(0, v10, acc1, sm.dg1, dgi1, rs10, rs11, rs12, rs13)
    DCOV_J(1, v11, acc1, sm.dg1, dgi1, rs10, rs11, rs12, rs13)
    DCOV_J(2, v12, acc1, sm.dg1, dgi1, rs10, rs11, rs12, rs13)
    DCOV_J(3, v13, acc1, sm.dg1, dgi1, rs10, rs11, rs12, rs13)

    #pragma unroll
    for (int off = 1; off < 16; off <<= 1) {
        rs00 += __shfl_xor(rs00, off, 64);
        rs01 += __shfl_xor(rs01, off, 64);
        rs02 += __shfl_xor(rs02, off, 64);
        rs03 += __shfl_xor(rs03, off, 64);
        rs10 += __shfl_xor(rs10, off, 64);
        rs11 += __shfl_xor(rs11, off, 64);
        rs12 += __shfl_xor(rs12, off, 64);
        rs13 += __shfl_xor(rs13, off, 64);
    }
    if (c15 == 0) {
        f32x4 rmv0 = {rs00*(1.0f/64.0f), rs01*(1.0f/64.0f),
                      rs02*(1.0f/64.0f), rs03*(1.0f/64.0f)};
        f32x4 rmv1 = {rs10*(1.0f/64.0f), rs11*(1.0f/64.0f),
                      rs12*(1.0f/64.0f), rs13*(1.0f/64.0f)};
        *(f32x4*)&sm.rm0[16*wv + 4*qd] = rmv0;
        *(f32x4*)&sm.rm1[16*wv + 4*qd] = rmv1;
    }
    float tt0 = (rs00 + rs01) + (rs02 + rs03);
    float tt1 = (rs10 + rs11) + (rs12 + rs13);
    tt0 += __shfl_xor(tt0, 16, 64);
    tt0 += __shfl_xor(tt0, 32, 64);
    tt1 += __shfl_xor(tt1, 16, 64);
    tt1 += __shfl_xor(tt1, 32, 64);
    if (lane == 0) { sm.w40[wv] = tt0; sm.w41[wv] = tt1; }
    __syncthreads();
    float tm0 = (sm.w40[0] + sm.w40[1] + sm.w40[2] + sm.w40[3]) * (1.0f/4096.0f);
    float tm1 = (sm.w41[0] + sm.w41[1] + sm.w41[2] + sm.w41[3]) * (1.0f/4096.0f);

    // ---- center both, write swizzled centered matrices
    {
        const float rmi00 = rs00*(1.0f/64.0f), rmi01 = rs01*(1.0f/64.0f),
                    rmi02 = rs02*(1.0f/64.0f), rmi03 = rs03*(1.0f/64.0f);
        const float rmi10 = rs10*(1.0f/64.0f), rmi11 = rs11*(1.0f/64.0f),
                    rmi12 = rs12*(1.0f/64.0f), rmi13 = rs13*(1.0f/64.0f);
        float* dc0 = sm.r0.dcov;
        float* dc1 = sm.r1.dcov;
        const int cch = 4*wv + qd;
        CENTER_J(0, v00, sm.rm0, dc0, tm0, rmi00, rmi01, rmi02, rmi03)
        CENTER_J(1, v01, sm.rm0, dc0, tm0, rmi00, rmi01, rmi02, rmi03)
        CENTER_J(2, v02, sm.rm0, dc0, tm0, rmi00, rmi01, rmi02, rmi03)
        CENTER_J(3, v03, sm.rm0, dc0, tm0, rmi00, rmi01, rmi02, rmi03)
        CENTER_J(0, v10, sm.rm1, dc1, tm1, rmi10, rmi11, rmi12, rmi13)
        CENTER_J(1, v11, sm.rm1, dc1, tm1, rmi10, rmi11, rmi12, rmi13)
        CENTER_J(2, v12, sm.rm1, dc1, tm1, rmi10, rmi11, rmi12, rmi13)
        CENTER_J(3, v13, sm.rm1, dc1, tm1, rmi10, rmi11, rmi12, rmi13)
    }
    __syncthreads();

    // ---- tail: one supT stream feeds BOTH queries (22 FMA / 48 B)
    float qq0 = 0.0f, qq1 = 0.0f;
    float cr0[NWAY], cr1[NWAY];        // constant-indexed only (unrolled)
    #pragma unroll
    for (int m = 0; m < NWAY; ++m) { cr0[m] = 0.0f; cr1[m] = 0.0f; }

    const float* dcov0 = sm.r0.dcov;
    const float* dcov1 = sm.r1.dcov;
    for (int k = tid; k < NTRI; k += 256) {
        unsigned t = table[k];
        float va = dcov0[t >> 16];
        float vb = dcov1[t >> 16];
        qq0 = fmaf(va, va, qq0);
        qq1 = fmaf(vb, vb, qq1);
        const float4* sp = (const float4*)(supT + (size_t)k * STP);
        float4 sa = sp[0], sb = sp[1], sc = sp[2];   // cols 10,11 pad
        cr0[0] = fmaf(va, sa.x, cr0[0]);  cr1[0] = fmaf(vb, sa.x, cr1[0]);
        cr0[1] = fmaf(va, sa.y, cr0[1]);  cr1[1] = fmaf(vb, sa.y, cr1[1]);
        cr0[2] = fmaf(va, sa.z, cr0[2]);  cr1[2] = fmaf(vb, sa.z, cr1[2]);
        cr0[3] = fmaf(va, sa.w, cr0[3]);  cr1[3] = fmaf(vb, sa.w, cr1[3]);
        cr0[4] = fmaf(va, sb.x, cr0[4]);  cr1[4] = fmaf(vb, sb.x, cr1[4]);
        cr0[5] = fmaf(va, sb.y, cr0[5]);  cr1[5] = fmaf(vb, sb.y, cr1[5]);
        cr0[6] = fmaf(va, sb.z, cr0[6]);  cr1[6] = fmaf(vb, sb.z, cr1[6]);
        cr0[7] = fmaf(va, sb.w, cr0[7]);  cr1[7] = fmaf(vb, sb.w, cr1[7]);
        cr0[8] = fmaf(va, sc.x, cr0[8]);  cr1[8] = fmaf(vb, sc.x, cr1[8]);
        cr0[9] = fmaf(va, sc.y, cr0[9]);  cr1[9] = fmaf(vb, sc.y, cr1[9]);
    }
    __syncthreads();                   // all dcov reads done -> part overlay safe

    // ---- transpose reduce, both queries (part0/part1 overlay the regions)
    float* part0 = (float*)&sm.r0;
    float* part1 = (float*)&sm.r1;
    {
        f32x4 p0 = {cr0[0], cr0[1], cr0[2], cr0[3]};
        f32x4 p1 = {cr0[4], cr0[5], cr0[6], cr0[7]};
        f32x4 p2 = {cr0[8], cr0[9], qq0, 0.0f};
        *(f32x4*)&part0[tid*12 + 0] = p0;
        *(f32x4*)&part0[tid*12 + 4] = p1;
        *(f32x4*)&part0[tid*12 + 8] = p2;
        f32x4 p3 = {cr1[0], cr1[1], cr1[2], cr1[3]};
        f32x4 p4 = {cr1[4], cr1[5], cr1[6], cr1[7]};
        f32x4 p5 = {cr1[8], cr1[9], qq1, 0.0f};
        *(f32x4*)&part1[tid*12 + 0] = p3;
        *(f32x4*)&part1[tid*12 + 4] = p4;
        *(f32x4*)&part1[tid*12 + 8] = p5;
    }
    __syncthreads();
    if (tid < 176) {
        int m = tid >> 4, g = tid & 15;
        float sA = 0.0f, sB = 0.0f;
        #pragma unroll
        for (int t = 0; t < 16; ++t) {
            sA += part0[(g + 16*t)*12 + m];
            sB += part1[(g + 16*t)*12 + m];
        }
        #pragma unroll
        for (int off = 1; off < 16; off <<= 1) {
            sA += __shfl_xor(sA, off, 64);
            sB += __shfl_xor(sB, off, 64);
        }
        if (g == 0) { sm.red0[m] = sA; sm.red1[m] = sB; }
    }
    __syncthreads();
    if (tid < NWAY) {
        out[(size_t)qn0 * NWAY + tid] = -(sm.red0[10] + s2[tid] - 2.0f*sm.red0[tid]);
        out[(size_t)qn1 * NWAY + tid] = -(sm.red1[10] + s2[tid] - 2.0f*sm.red1[tid]);
    }
}

// Softmax NLL partials: one atomicAdd per block.
__global__ __launch_bounds__(256) void kern_loss(const float* __restrict__ score,
                                                 const int* __restrict__ label,
                                                 float* __restrict__ loss_out) {
    __shared__ float red[4];
    int n = blockIdx.x * 256 + threadIdx.x;
    float lsum = 0.0f;
    if (n < NQRY) {
        const float* srow = score + (size_t)n * NWAY;
        float s[NWAY];
        float mx = -1e30f;
        #pragma unroll
        for (int m = 0; m < NWAY; ++m) { s[m] = srow[m]; mx = fmaxf(mx, s[m]); }
        float se = 0.0f;
        #pragma unroll
        for (int m = 0; m < NWAY; ++m) se += __expf(s[m] - mx);
        float lse = mx + __logf(se);
        lsum = lse - s[label[n]];
    }
    int lane = threadIdx.x & 63, wv = threadIdx.x >> 6;
    #pragma unroll
    for (int off = 32; off > 0; off >>= 1) lsum += __shfl_xor(lsum, off, 64);
    if (lane == 0) red[wv] = lsum;
    __syncthreads();
    if (threadIdx.x == 0)
        atomicAdd(loss_out, (red[0] + red[1] + red[2] + red[3]) * (1.0f / (float)NQRY));
}

extern "C" void kernel_launch(void* const* d_in, const int* in_sizes, int n_in,
                              void* d_out, int out_size, void* d_ws, size_t ws_size,
                              hipStream_t stream) {
    (void)in_sizes; (void)n_in; (void)out_size; (void)ws_size;
    const float* feat = (const float*)d_in[0];
    const float* temp = (const float*)d_in[1];
    const int*   label = (const int*)d_in[2];
    float* out = (float*)d_out;

    // workspace layout (~6.8 MB):
    float*    tv    = (float*)d_ws;                  // 800*2080 f = 6.656 MB
    float*    supT  = tv + (size_t)NSUP * NTRI;      // 2080*12 f (transposed+pad)
    float*    s2    = supT + NTRI*STP;               // 10 f (+pad)
    unsigned* table = (unsigned*)(s2 + 16);          // 2080 u32
    float* loss_slot = out + (size_t)NQRY * NWAY;

    kern_init<<<(NTRI + 255)/256, 256, 0, stream>>>(table, s2, loss_slot);
    kern_support<<<NSUP, 256, 0, stream>>>(feat, temp, tv);
    kern_reduce<<<NWAY*9, 256, 0, stream>>>(tv, table, supT, s2);
    kern_query<<<NQRY/2, 256, 0, stream>>>(feat, temp, table, supT, s2, out);
    kern_loss<<<(NQRY + 255)/256, 256, 0, stream>>>(out, label, loss_slot);
}